// Round 2
// baseline (886.115 us; speedup 1.0000x reference)
//
#include <hip/hip_runtime.h>
#include <hip/hip_bf16.h>
#include <cstdint>

// Problem constants (match reference)
#define NN   100000   // nodes
#define DD   128      // in features
#define HH   64       // hidden
#define CC   40       // classes
#define NNZE 3200000  // edges

// ---------------- gcn_norm prep ----------------

__global__ void k_init(float* deg, int* cnt, int n) {
    int i = blockIdx.x * blockDim.x + threadIdx.x;
    if (i < n) { deg[i] = 1.0f; cnt[i] = 0; }   // self-loop weight 1
}

__global__ void k_count(const int* __restrict__ col, const float* __restrict__ w,
                        float* deg, int* cnt, int nnz) {
    int e = blockIdx.x * blockDim.x + threadIdx.x;
    if (e < nnz) {
        int c = col[e];
        atomicAdd(&deg[c], w[e]);
        atomicAdd(&cnt[c], 1);
    }
}

__global__ void k_dis(const float* __restrict__ deg, float* dis, int n) {
    int i = blockIdx.x * blockDim.x + threadIdx.x;
    if (i < n) { float d = deg[i]; dis[i] = d > 0.f ? rsqrtf(d) : 0.f; }
}

// ---------------- exclusive scan of cnt -> offs (3 kernels) ----------------
// tile = 1024 elements per block (256 threads x 4)

__global__ void scan_k1(const int* __restrict__ cnt, int* offs, int* bsum, int n) {
    __shared__ int s[256];
    int t = threadIdx.x, b = blockIdx.x;
    int base = b * 1024 + t * 4;
    int v0 = (base + 0 < n) ? cnt[base + 0] : 0;
    int v1 = (base + 1 < n) ? cnt[base + 1] : 0;
    int v2 = (base + 2 < n) ? cnt[base + 2] : 0;
    int v3 = (base + 3 < n) ? cnt[base + 3] : 0;
    int tsum = v0 + v1 + v2 + v3;
    s[t] = tsum;
    __syncthreads();
    for (int off = 1; off < 256; off <<= 1) {
        int x = (t >= off) ? s[t - off] : 0;
        __syncthreads();
        s[t] += x;
        __syncthreads();
    }
    int incl = s[t];
    int p = incl - tsum;  // exclusive base for this thread
    if (base + 0 < n) offs[base + 0] = p; p += v0;
    if (base + 1 < n) offs[base + 1] = p; p += v1;
    if (base + 2 < n) offs[base + 2] = p; p += v2;
    if (base + 3 < n) offs[base + 3] = p;
    if (t == 255) bsum[b] = incl;  // block total
}

__global__ void scan_k2(int* bsum, int nb, int* offs, int n) {
    if (threadIdx.x == 0 && blockIdx.x == 0) {
        int run = 0;
        for (int i = 0; i < nb; i++) { int v = bsum[i]; bsum[i] = run; run += v; }
        offs[n] = run;  // total edge count
    }
}

__global__ void scan_k3(int* offs, const int* __restrict__ bsum, int* cursor, int n) {
    int i = blockIdx.x * blockDim.x + threadIdx.x;
    if (i < n) { int v = offs[i] + bsum[i >> 10]; offs[i] = v; cursor[i] = v; }
}

// ---------------- CSR fill ----------------

__global__ void k_fill(const int* __restrict__ row, const int* __restrict__ col,
                       const float* __restrict__ w, const float* __restrict__ dis,
                       int* cursor, int* csr_src, float* csr_a, int nnz) {
    int e = blockIdx.x * blockDim.x + threadIdx.x;
    if (e < nnz) {
        int c = col[e], r = row[e];
        int pos = atomicAdd(&cursor[c], 1);
        csr_src[pos] = r;
        csr_a[pos] = dis[r] * w[e];   // dis[col] factor applied at epilogue
    }
}

// ---------------- GEMM1: h1 = x @ W1  (100000x128 @ 128x64, fp32 vector) -----

__global__ __launch_bounds__(256) void k_gemm1(const float* __restrict__ x,
                                               const float* __restrict__ W1,
                                               float* __restrict__ h1, int n) {
    __shared__ float ws[128 * 64];   // W1 [k][c]
    __shared__ float xs[16 * 129];   // 16 rows, padded stride 129
    int t = threadIdx.x;
    for (int i = t; i < 128 * 64; i += 256) ws[i] = W1[i];
    int row0 = blockIdx.x * 64;
    int r = t >> 4, cg = t & 15;
    for (int p = 0; p < 4; p++) {
        __syncthreads();  // protect xs (and ws on first pass)
        int rbase = row0 + p * 16;
        // stage 16x128 floats (512 float4)
        for (int i = t; i < 512; i += 256) {
            int li = i * 4;
            int rr = li >> 7, kk = li & 127;
            float4 v = make_float4(0.f, 0.f, 0.f, 0.f);
            if (rbase + rr < n) v = *(const float4*)&x[(rbase + rr) * 128 + kk];
            xs[rr * 129 + kk + 0] = v.x;
            xs[rr * 129 + kk + 1] = v.y;
            xs[rr * 129 + kk + 2] = v.z;
            xs[rr * 129 + kk + 3] = v.w;
        }
        __syncthreads();
        float4 acc = make_float4(0.f, 0.f, 0.f, 0.f);
        for (int k = 0; k < 128; k++) {
            float xa = xs[r * 129 + k];
            float4 w4 = *(const float4*)&ws[k * 64 + cg * 4];
            acc.x += xa * w4.x; acc.y += xa * w4.y;
            acc.z += xa * w4.z; acc.w += xa * w4.w;
        }
        int rowi = rbase + r;
        if (rowi < n) *(float4*)&h1[rowi * 64 + cg * 4] = acc;
    }
}

// ------- agg1 + bias + relu + matvec W2 fused: g = relu(A~ h1 + b1) @ W2 -----
// one wave per destination node; lane = feature (H=64)

__global__ __launch_bounds__(256) void k_agg1(const float* __restrict__ h1,
                                              const int* __restrict__ offs,
                                              const int* __restrict__ csr_src,
                                              const float* __restrict__ csr_a,
                                              const float* __restrict__ dis,
                                              const float* __restrict__ b1,
                                              const float* __restrict__ W2,
                                              float* __restrict__ g, int n) {
    __shared__ float w2s[64 * 40];
    __shared__ float sh2[4][64];
    __shared__ int   ssrc[4][64];
    __shared__ float sa[4][64];
    int t = threadIdx.x;
    for (int i = t; i < 64 * 40; i += 256) w2s[i] = W2[i];
    __syncthreads();
    int w = t >> 6, l = t & 63;
    int c = blockIdx.x * 4 + w;
    if (c >= n) return;
    float dc = dis[c];
    float selfh = h1[c * 64 + l];
    float acc = 0.f;
    int start = offs[c], end = offs[c + 1];
    for (int base = start; base < end; base += 64) {
        int m = end - base; if (m > 64) m = 64;
        if (l < m) { ssrc[w][l] = csr_src[base + l]; sa[w][l] = csr_a[base + l]; }
        for (int j = 0; j < m; j++) {
            acc += sa[w][j] * h1[ssrc[w][j] * 64 + l];
        }
    }
    float hv = dc * acc + dc * dc * selfh + b1[l];
    hv = hv > 0.f ? hv : 0.f;
    sh2[w][l] = hv;
    if (l < 40) {
        float gv = 0.f;
        for (int k = 0; k < 64; k++) gv += sh2[w][k] * w2s[k * 40 + l];
        g[c * 40 + l] = gv;
    }
}

// ---------------- agg2 + bias: out = A~ g + b2 ----------------

__global__ __launch_bounds__(256) void k_agg2(const float* __restrict__ g,
                                              const int* __restrict__ offs,
                                              const int* __restrict__ csr_src,
                                              const float* __restrict__ csr_a,
                                              const float* __restrict__ dis,
                                              const float* __restrict__ b2,
                                              float* __restrict__ out, int n) {
    __shared__ int   ssrc[4][64];
    __shared__ float sa[4][64];
    int t = threadIdx.x;
    int w = t >> 6, l = t & 63;
    int c = blockIdx.x * 4 + w;
    if (c >= n) return;
    float dc = dis[c];
    float acc = 0.f;
    int start = offs[c], end = offs[c + 1];
    for (int base = start; base < end; base += 64) {
        int m = end - base; if (m > 64) m = 64;
        if (l < m) { ssrc[w][l] = csr_src[base + l]; sa[w][l] = csr_a[base + l]; }
        if (l < 40) {
            for (int j = 0; j < m; j++) {
                acc += sa[w][j] * g[ssrc[w][j] * 40 + l];
            }
        }
    }
    if (l < 40) {
        float selfg = g[c * 40 + l];
        out[c * 40 + l] = dc * acc + dc * dc * selfg + b2[l];
    }
}

// ---------------- launch ----------------

extern "C" void kernel_launch(void* const* d_in, const int* in_sizes, int n_in,
                              void* d_out, int out_size, void* d_ws, size_t ws_size,
                              hipStream_t stream) {
    const float* x  = (const float*)d_in[0];
    const int*   ei = (const int*)d_in[1];       // (2, NNZ): [0]=row(src), [1]=col(dst)
    const float* ew = (const float*)d_in[2];
    const float* W1 = (const float*)d_in[3];
    const float* b1 = (const float*)d_in[4];
    const float* W2 = (const float*)d_in[5];
    const float* b2 = (const float*)d_in[6];
    float* out = (float*)d_out;

    const int n = NN, nnz = NNZE;
    const int* erow = ei;
    const int* ecol = ei + nnz;

    // workspace layout (all 256B aligned)
    char* p = (char*)d_ws;
    auto alloc = [&](size_t bytes) {
        void* r = (void*)p;
        p += (bytes + 255) & ~(size_t)255;
        return r;
    };
    float* deg     = (float*)alloc((size_t)n * 4);
    float* dis     = (float*)alloc((size_t)n * 4);
    int*   offs    = (int*)  alloc((size_t)(n + 1) * 4);
    int*   cursor  = (int*)  alloc((size_t)n * 4);
    int*   cnt     = (int*)  alloc((size_t)n * 4);
    int*   bsum    = (int*)  alloc((size_t)128 * 4);
    int*   csr_src = (int*)  alloc((size_t)nnz * 4);
    float* csr_a   = (float*)alloc((size_t)nnz * 4);
    float* h1      = (float*)alloc((size_t)n * HH * 4);
    float* g       = (float*)alloc((size_t)n * CC * 4);
    (void)ws_size;

    const int NB_N   = (n + 255) / 256;
    const int NB_E   = (nnz + 255) / 256;
    const int NB_SC  = (n + 1023) / 1024;  // 98

    k_init<<<NB_N, 256, 0, stream>>>(deg, cnt, n);
    k_count<<<NB_E, 256, 0, stream>>>(ecol, ew, deg, cnt, nnz);
    k_dis<<<NB_N, 256, 0, stream>>>(deg, dis, n);
    scan_k1<<<NB_SC, 256, 0, stream>>>(cnt, offs, bsum, n);
    scan_k2<<<1, 64, 0, stream>>>(bsum, NB_SC, offs, n);
    scan_k3<<<NB_N, 256, 0, stream>>>(offs, bsum, cursor, n);
    k_fill<<<NB_E, 256, 0, stream>>>(erow, ecol, ew, dis, cursor, csr_src, csr_a, nnz);
    k_gemm1<<<(n + 63) / 64, 256, 0, stream>>>(x, W1, h1, n);
    k_agg1<<<(n + 3) / 4, 256, 0, stream>>>(h1, offs, csr_src, csr_a, dis, b1, W2, g, n);
    k_agg2<<<(n + 3) / 4, 256, 0, stream>>>(g, offs, csr_src, csr_a, dis, b2, out, n);
}

// Round 3
// 696.413 us; speedup vs baseline: 1.2724x; 1.2724x over previous
//
#include <hip/hip_runtime.h>
#include <hip/hip_bf16.h>
#include <cstdint>

// Problem constants (match reference)
#define NN   100000   // nodes
#define DD   128      // in features
#define HH   64       // hidden
#define CC   40       // classes
#define NNZE 3200000  // edges

// ---------------- histogram: one int atomic per edge, keep rank ------------

__global__ void k_zero(int* cnt, int n) {
    int i = blockIdx.x * blockDim.x + threadIdx.x;
    if (i < n) cnt[i] = 0;
}

__global__ void k_count(const int* __restrict__ col, int* cnt, int* rank, int nnz) {
    int e = blockIdx.x * blockDim.x + threadIdx.x;
    if (e < nnz) rank[e] = atomicAdd(&cnt[col[e]], 1);
}

// ---------------- exclusive scan of cnt -> offs (3 kernels) ----------------
// tile = 1024 elements per block (256 threads x 4)

__global__ void scan_k1(const int* __restrict__ cnt, int* offs, int* bsum, int n) {
    __shared__ int s[256];
    int t = threadIdx.x, b = blockIdx.x;
    int base = b * 1024 + t * 4;
    int v0 = (base + 0 < n) ? cnt[base + 0] : 0;
    int v1 = (base + 1 < n) ? cnt[base + 1] : 0;
    int v2 = (base + 2 < n) ? cnt[base + 2] : 0;
    int v3 = (base + 3 < n) ? cnt[base + 3] : 0;
    int tsum = v0 + v1 + v2 + v3;
    s[t] = tsum;
    __syncthreads();
    for (int off = 1; off < 256; off <<= 1) {
        int x = (t >= off) ? s[t - off] : 0;
        __syncthreads();
        s[t] += x;
        __syncthreads();
    }
    int incl = s[t];
    int p = incl - tsum;  // exclusive base for this thread
    if (base + 0 < n) offs[base + 0] = p; p += v0;
    if (base + 1 < n) offs[base + 1] = p; p += v1;
    if (base + 2 < n) offs[base + 2] = p; p += v2;
    if (base + 3 < n) offs[base + 3] = p;
    if (t == 255) bsum[b] = incl;  // block total
}

__global__ void scan_k2(int* bsum, int nb, int* offs, int n) {
    if (threadIdx.x == 0 && blockIdx.x == 0) {
        int run = 0;
        for (int i = 0; i < nb; i++) { int v = bsum[i]; bsum[i] = run; run += v; }
        offs[n] = run;  // total edge count
    }
}

__global__ void scan_k3(int* offs, const int* __restrict__ bsum, int n) {
    int i = blockIdx.x * blockDim.x + threadIdx.x;
    if (i < n) offs[i] += bsum[i >> 10];
}

// ---------------- CSR fill (atomic-free: pos = offs[col] + rank) -----------

__global__ void k_fill(const int* __restrict__ row, const int* __restrict__ col,
                       const float* __restrict__ w, const int* __restrict__ rank,
                       const int* __restrict__ offs,
                       int* csr_src, float* csr_a, int nnz) {
    int e = blockIdx.x * blockDim.x + threadIdx.x;
    if (e < nnz) {
        int pos = offs[col[e]] + rank[e];
        csr_src[pos] = row[e];
        csr_a[pos] = w[e];            // raw weight; scaled by dis[src] later
    }
}

// ---------------- deg -> dis (per-node contiguous sum, no atomics) ---------

__global__ void k_degdis(const int* __restrict__ offs, const float* __restrict__ csr_a,
                         float* dis, int n) {
    int i = blockIdx.x * blockDim.x + threadIdx.x;
    if (i < n) {
        float s = 1.0f;               // self-loop weight
        int e0 = offs[i], e1 = offs[i + 1];
        for (int j = e0; j < e1; j++) s += csr_a[j];
        dis[i] = s > 0.f ? rsqrtf(s) : 0.f;
    }
}

// ---------------- fold dis[src] into csr_a ----------------

__global__ void k_scale(float* csr_a, const int* __restrict__ csr_src,
                        const float* __restrict__ dis, int nnz) {
    int i = blockIdx.x * blockDim.x + threadIdx.x;
    if (i < nnz) csr_a[i] *= dis[csr_src[i]];
}

// ---------------- GEMM1: h1 = x @ W1  (100000x128 @ 128x64, fp32 vector) ---

__global__ __launch_bounds__(256) void k_gemm1(const float* __restrict__ x,
                                               const float* __restrict__ W1,
                                               float* __restrict__ h1, int n) {
    __shared__ float ws[128 * 64];   // W1 [k][c]
    __shared__ float xs[16 * 129];   // 16 rows, padded stride 129
    int t = threadIdx.x;
    for (int i = t; i < 128 * 64; i += 256) ws[i] = W1[i];
    int row0 = blockIdx.x * 64;
    int r = t >> 4, cg = t & 15;
    for (int p = 0; p < 4; p++) {
        __syncthreads();  // protect xs (and ws on first pass)
        int rbase = row0 + p * 16;
        for (int i = t; i < 512; i += 256) {
            int li = i * 4;
            int rr = li >> 7, kk = li & 127;
            float4 v = make_float4(0.f, 0.f, 0.f, 0.f);
            if (rbase + rr < n) v = *(const float4*)&x[(rbase + rr) * 128 + kk];
            xs[rr * 129 + kk + 0] = v.x;
            xs[rr * 129 + kk + 1] = v.y;
            xs[rr * 129 + kk + 2] = v.z;
            xs[rr * 129 + kk + 3] = v.w;
        }
        __syncthreads();
        float4 acc = make_float4(0.f, 0.f, 0.f, 0.f);
        for (int k = 0; k < 128; k++) {
            float xa = xs[r * 129 + k];
            float4 w4 = *(const float4*)&ws[k * 64 + cg * 4];
            acc.x += xa * w4.x; acc.y += xa * w4.y;
            acc.z += xa * w4.z; acc.w += xa * w4.w;
        }
        int rowi = rbase + r;
        if (rowi < n) *(float4*)&h1[rowi * 64 + cg * 4] = acc;
    }
}

// ------- agg1 + bias + relu + matvec W2 fused: g = relu(A~ h1 + b1) @ W2 ----
// one wave per destination node; lane = feature (H=64)

__global__ __launch_bounds__(256) void k_agg1(const float* __restrict__ h1,
                                              const int* __restrict__ offs,
                                              const int* __restrict__ csr_src,
                                              const float* __restrict__ csr_a,
                                              const float* __restrict__ dis,
                                              const float* __restrict__ b1,
                                              const float* __restrict__ W2,
                                              float* __restrict__ g, int n) {
    __shared__ float w2s[64 * 40];
    __shared__ float sh2[4][64];
    __shared__ int   ssrc[4][64];
    __shared__ float sa[4][64];
    int t = threadIdx.x;
    for (int i = t; i < 64 * 40; i += 256) w2s[i] = W2[i];
    __syncthreads();
    int w = t >> 6, l = t & 63;
    int c = blockIdx.x * 4 + w;
    if (c >= n) return;
    float dc = dis[c];
    float selfh = h1[c * 64 + l];
    float acc = 0.f;
    int start = offs[c], end = offs[c + 1];
    for (int base = start; base < end; base += 64) {
        int m = end - base; if (m > 64) m = 64;
        if (l < m) { ssrc[w][l] = csr_src[base + l]; sa[w][l] = csr_a[base + l]; }
        for (int j = 0; j < m; j++) {
            acc += sa[w][j] * h1[ssrc[w][j] * 64 + l];
        }
    }
    float hv = dc * acc + dc * dc * selfh + b1[l];
    hv = hv > 0.f ? hv : 0.f;
    sh2[w][l] = hv;
    if (l < 40) {
        float gv = 0.f;
        for (int k = 0; k < 64; k++) gv += sh2[w][k] * w2s[k * 40 + l];
        g[c * 40 + l] = gv;
    }
}

// ---------------- agg2 + bias: out = A~ g + b2 ----------------

__global__ __launch_bounds__(256) void k_agg2(const float* __restrict__ g,
                                              const int* __restrict__ offs,
                                              const int* __restrict__ csr_src,
                                              const float* __restrict__ csr_a,
                                              const float* __restrict__ dis,
                                              const float* __restrict__ b2,
                                              float* __restrict__ out, int n) {
    __shared__ int   ssrc[4][64];
    __shared__ float sa[4][64];
    int t = threadIdx.x;
    int w = t >> 6, l = t & 63;
    int c = blockIdx.x * 4 + w;
    if (c >= n) return;
    float dc = dis[c];
    float acc = 0.f;
    int start = offs[c], end = offs[c + 1];
    for (int base = start; base < end; base += 64) {
        int m = end - base; if (m > 64) m = 64;
        if (l < m) { ssrc[w][l] = csr_src[base + l]; sa[w][l] = csr_a[base + l]; }
        if (l < 40) {
            for (int j = 0; j < m; j++) {
                acc += sa[w][j] * g[ssrc[w][j] * 40 + l];
            }
        }
    }
    if (l < 40) {
        float selfg = g[c * 40 + l];
        out[c * 40 + l] = dc * acc + dc * dc * selfg + b2[l];
    }
}

// ---------------- launch ----------------

extern "C" void kernel_launch(void* const* d_in, const int* in_sizes, int n_in,
                              void* d_out, int out_size, void* d_ws, size_t ws_size,
                              hipStream_t stream) {
    const float* x  = (const float*)d_in[0];
    const int*   ei = (const int*)d_in[1];       // (2, NNZ): [0]=row(src), [1]=col(dst)
    const float* ew = (const float*)d_in[2];
    const float* W1 = (const float*)d_in[3];
    const float* b1 = (const float*)d_in[4];
    const float* W2 = (const float*)d_in[5];
    const float* b2 = (const float*)d_in[6];
    float* out = (float*)d_out;

    const int n = NN, nnz = NNZE;
    const int* erow = ei;
    const int* ecol = ei + nnz;

    // workspace layout (lifetime-aware aliasing; stays within round-2's
    // proven ~68.8MB footprint)
    char* p = (char*)d_ws;
    auto alloc = [&](size_t bytes) {
        void* r = (void*)p;
        p += (bytes + 255) & ~(size_t)255;
        return r;
    };
    float* dis     = (float*)alloc((size_t)n * 4);
    int*   offs    = (int*)  alloc((size_t)(n + 1) * 4);
    int*   cnt     = (int*)  alloc((size_t)n * 4);          // dead after scan_k1
    int*   bsum    = (int*)  alloc((size_t)128 * 4);
    int*   csr_src = (int*)  alloc((size_t)nnz * 4);
    float* csr_a   = (float*)alloc((size_t)nnz * 4);
    float* h1      = (float*)alloc((size_t)n * HH * 4);     // born at k_gemm1
    float* g       = (float*)alloc((size_t)n * CC * 4);
    int*   rank    = (int*)h1;   // alias: rank (nnz*4 = 12.8MB) dies at k_fill,
                                 // h1 (25.6MB) is written afterwards by k_gemm1
    (void)ws_size;

    const int NB_N   = (n + 255) / 256;
    const int NB_E   = (nnz + 255) / 256;
    const int NB_SC  = (n + 1023) / 1024;  // 98

    k_zero  <<<NB_N, 256, 0, stream>>>(cnt, n);
    k_count <<<NB_E, 256, 0, stream>>>(ecol, cnt, rank, nnz);
    scan_k1 <<<NB_SC, 256, 0, stream>>>(cnt, offs, bsum, n);
    scan_k2 <<<1, 64, 0, stream>>>(bsum, NB_SC, offs, n);
    scan_k3 <<<NB_N, 256, 0, stream>>>(offs, bsum, n);
    k_fill  <<<NB_E, 256, 0, stream>>>(erow, ecol, ew, rank, offs, csr_src, csr_a, nnz);
    k_degdis<<<NB_N, 256, 0, stream>>>(offs, csr_a, dis, n);
    k_scale <<<NB_E, 256, 0, stream>>>(csr_a, csr_src, dis, nnz);
    k_gemm1 <<<(n + 63) / 64, 256, 0, stream>>>(x, W1, h1, n);
    k_agg1  <<<(n + 3) / 4, 256, 0, stream>>>(h1, offs, csr_src, csr_a, dis, b1, W2, g, n);
    k_agg2  <<<(n + 3) / 4, 256, 0, stream>>>(g, offs, csr_src, csr_a, dis, b2, out, n);
}

// Round 5
// 629.867 us; speedup vs baseline: 1.4068x; 1.1057x over previous
//
#include <hip/hip_runtime.h>
#include <hip/hip_bf16.h>
#include <cstdint>

// Problem constants (match reference)
#define NN   100000   // nodes
#define DD   128      // in features
#define HH   64       // hidden
#define CC   40       // classes
#define NNZE 3200000  // edges

// ---------------- histogram: one returning atomic per edge, 4 edges/thread --

__global__ void k_zero(int* cnt, int n) {
    int i = blockIdx.x * blockDim.x + threadIdx.x;
    if (i < n) cnt[i] = 0;
}

__global__ void k_count(const int* __restrict__ col, int* cnt, int* rank, int nnz4) {
    int i = blockIdx.x * blockDim.x + threadIdx.x;
    if (i < nnz4) {
        int4 c = ((const int4*)col)[i];
        int r0 = atomicAdd(&cnt[c.x], 1);
        int r1 = atomicAdd(&cnt[c.y], 1);
        int r2 = atomicAdd(&cnt[c.z], 1);
        int r3 = atomicAdd(&cnt[c.w], 1);
        ((int4*)rank)[i] = make_int4(r0, r1, r2, r3);
    }
}

// ---------------- exclusive scan of cnt -> offs (3 kernels) ----------------
// tile = 1024 elements per block (256 threads x 4)

__global__ void scan_k1(const int* __restrict__ cnt, int* offs, int* bsum, int n) {
    __shared__ int s[256];
    int t = threadIdx.x, b = blockIdx.x;
    int base = b * 1024 + t * 4;
    int v0 = (base + 0 < n) ? cnt[base + 0] : 0;
    int v1 = (base + 1 < n) ? cnt[base + 1] : 0;
    int v2 = (base + 2 < n) ? cnt[base + 2] : 0;
    int v3 = (base + 3 < n) ? cnt[base + 3] : 0;
    int tsum = v0 + v1 + v2 + v3;
    s[t] = tsum;
    __syncthreads();
    for (int off = 1; off < 256; off <<= 1) {
        int x = (t >= off) ? s[t - off] : 0;
        __syncthreads();
        s[t] += x;
        __syncthreads();
    }
    int incl = s[t];
    int p = incl - tsum;  // exclusive base for this thread
    if (base + 0 < n) offs[base + 0] = p; p += v0;
    if (base + 1 < n) offs[base + 1] = p; p += v1;
    if (base + 2 < n) offs[base + 2] = p; p += v2;
    if (base + 3 < n) offs[base + 3] = p;
    if (t == 255) bsum[b] = incl;  // block total
}

__global__ void scan_k2(int* bsum, int nb, int* offs, int n) {
    if (threadIdx.x == 0 && blockIdx.x == 0) {
        int run = 0;
        for (int i = 0; i < nb; i++) { int v = bsum[i]; bsum[i] = run; run += v; }
        offs[n] = run;  // total edge count
    }
}

__global__ void scan_k3(int* offs, const int* __restrict__ bsum, int n) {
    int i = blockIdx.x * blockDim.x + threadIdx.x;
    if (i < n) offs[i] += bsum[i >> 10];
}

// -------- CSR fill (atomic-free, packed int2 {src, w}, 4 edges/thread) -----

__global__ void k_fill(const int* __restrict__ row, const int* __restrict__ col,
                       const float* __restrict__ w, const int* __restrict__ rank,
                       const int* __restrict__ offs,
                       int2* __restrict__ csr, int nnz4) {
    int i = blockIdx.x * blockDim.x + threadIdx.x;
    if (i < nnz4) {
        int4   r  = ((const int4*)row)[i];
        int4   c  = ((const int4*)col)[i];
        int4   rk = ((const int4*)rank)[i];
        float4 wv = ((const float4*)w)[i];
        csr[offs[c.x] + rk.x] = make_int2(r.x, __float_as_int(wv.x));
        csr[offs[c.y] + rk.y] = make_int2(r.y, __float_as_int(wv.y));
        csr[offs[c.z] + rk.z] = make_int2(r.z, __float_as_int(wv.z));
        csr[offs[c.w] + rk.w] = make_int2(r.w, __float_as_int(wv.w));
    }
}

// ---------------- deg -> dis (per-node contiguous sum, no atomics) ---------

__global__ void k_degdis(const int* __restrict__ offs, const int2* __restrict__ csr,
                         float* dis, int n) {
    int i = blockIdx.x * blockDim.x + threadIdx.x;
    if (i < n) {
        float s = 1.0f;               // self-loop weight
        int e0 = offs[i], e1 = offs[i + 1];
        for (int j = e0; j < e1; j++) s += __int_as_float(csr[j].y);
        dis[i] = s > 0.f ? rsqrtf(s) : 0.f;
    }
}

// ---------------- GEMM1: h1 = x @ W1  (100000x128 @ 128x64, fp32 vector) ---

__global__ __launch_bounds__(256) void k_gemm1(const float* __restrict__ x,
                                               const float* __restrict__ W1,
                                               float* __restrict__ h1, int n) {
    __shared__ float ws[128 * 64];   // W1 [k][c]
    __shared__ float xs[16 * 129];   // 16 rows, padded stride 129
    int t = threadIdx.x;
    for (int i = t; i < 128 * 64; i += 256) ws[i] = W1[i];
    int row0 = blockIdx.x * 64;
    int r = t >> 4, cg = t & 15;
    for (int p = 0; p < 4; p++) {
        __syncthreads();  // protect xs (and ws on first pass)
        int rbase = row0 + p * 16;
        for (int i = t; i < 512; i += 256) {
            int li = i * 4;
            int rr = li >> 7, kk = li & 127;
            float4 v = make_float4(0.f, 0.f, 0.f, 0.f);
            if (rbase + rr < n) v = *(const float4*)&x[(rbase + rr) * 128 + kk];
            xs[rr * 129 + kk + 0] = v.x;
            xs[rr * 129 + kk + 1] = v.y;
            xs[rr * 129 + kk + 2] = v.z;
            xs[rr * 129 + kk + 3] = v.w;
        }
        __syncthreads();
        float4 acc = make_float4(0.f, 0.f, 0.f, 0.f);
        for (int k = 0; k < 128; k++) {
            float xa = xs[r * 129 + k];
            float4 w4 = *(const float4*)&ws[k * 64 + cg * 4];
            acc.x += xa * w4.x; acc.y += xa * w4.y;
            acc.z += xa * w4.z; acc.w += xa * w4.w;
        }
        int rowi = rbase + r;
        if (rowi < n) *(float4*)&h1[rowi * 64 + cg * 4] = acc;
    }
}

// ------- agg1 + bias + relu + matvec W2 fused: g = relu(A~ h1 + b1) @ W2 ----
// one wave per destination node; lane = feature (H=64)
// dis[src] folded into staging (replaces the old k_scale pass)

__global__ __launch_bounds__(256) void k_agg1(const float* __restrict__ h1,
                                              const int* __restrict__ offs,
                                              const int2* __restrict__ csr,
                                              const float* __restrict__ dis,
                                              const float* __restrict__ b1,
                                              const float* __restrict__ W2,
                                              float* __restrict__ g, int n) {
    __shared__ float w2s[64 * 40];
    __shared__ float sh2[4][64];
    __shared__ int   ssrc[4][64];
    __shared__ float sa[4][64];
    int t = threadIdx.x;
    for (int i = t; i < 64 * 40; i += 256) w2s[i] = W2[i];
    __syncthreads();
    int w = t >> 6, l = t & 63;
    int c = blockIdx.x * 4 + w;
    if (c >= n) return;
    float dc = dis[c];
    float selfh = h1[c * 64 + l];
    float acc = 0.f;
    int start = offs[c], end = offs[c + 1];
    for (int base = start; base < end; base += 64) {
        int m = end - base; if (m > 64) m = 64;
        if (l < m) {
            int2 pk = csr[base + l];
            ssrc[w][l] = pk.x;
            sa[w][l] = __int_as_float(pk.y) * dis[pk.x];
        }
        for (int j = 0; j < m; j++) {
            acc += sa[w][j] * h1[ssrc[w][j] * 64 + l];
        }
    }
    float hv = dc * acc + dc * dc * selfh + b1[l];
    hv = hv > 0.f ? hv : 0.f;
    sh2[w][l] = hv;
    if (l < 40) {
        float gv = 0.f;
        for (int k = 0; k < 64; k++) gv += sh2[w][k] * w2s[k * 40 + l];
        g[c * 40 + l] = gv;
    }
}

// ---------------- agg2 + bias: out = A~ g + b2 ----------------

__global__ __launch_bounds__(256) void k_agg2(const float* __restrict__ g,
                                              const int* __restrict__ offs,
                                              const int2* __restrict__ csr,
                                              const float* __restrict__ dis,
                                              const float* __restrict__ b2,
                                              float* __restrict__ out, int n) {
    __shared__ int   ssrc[4][64];
    __shared__ float sa[4][64];
    int t = threadIdx.x;
    int w = t >> 6, l = t & 63;
    int c = blockIdx.x * 4 + w;
    if (c >= n) return;
    float dc = dis[c];
    float acc = 0.f;
    int start = offs[c], end = offs[c + 1];
    for (int base = start; base < end; base += 64) {
        int m = end - base; if (m > 64) m = 64;
        if (l < m) {
            int2 pk = csr[base + l];
            ssrc[w][l] = pk.x;
            sa[w][l] = __int_as_float(pk.y) * dis[pk.x];
        }
        if (l < 40) {
            for (int j = 0; j < m; j++) {
                acc += sa[w][j] * g[ssrc[w][j] * 40 + l];
            }
        }
    }
    if (l < 40) {
        float selfg = g[c * 40 + l];
        out[c * 40 + l] = dc * acc + dc * dc * selfg + b2[l];
    }
}

// ---------------- launch ----------------

extern "C" void kernel_launch(void* const* d_in, const int* in_sizes, int n_in,
                              void* d_out, int out_size, void* d_ws, size_t ws_size,
                              hipStream_t stream) {
    const float* x  = (const float*)d_in[0];
    const int*   ei = (const int*)d_in[1];       // (2, NNZ): [0]=row(src), [1]=col(dst)
    const float* ew = (const float*)d_in[2];
    const float* W1 = (const float*)d_in[3];
    const float* b1 = (const float*)d_in[4];
    const float* W2 = (const float*)d_in[5];
    const float* b2 = (const float*)d_in[6];
    float* out = (float*)d_out;

    const int n = NN, nnz = NNZE;
    const int* erow = ei;
    const int* ecol = ei + nnz;

    // workspace layout (lifetime-aware aliasing)
    char* p = (char*)d_ws;
    auto alloc = [&](size_t bytes) {
        void* r = (void*)p;
        p += (bytes + 255) & ~(size_t)255;
        return r;
    };
    float* dis  = (float*)alloc((size_t)n * 4);
    int*   offs = (int*)  alloc((size_t)(n + 1) * 4);
    int*   cnt  = (int*)  alloc((size_t)n * 4);          // dead after scan_k1
    int*   bsum = (int*)  alloc((size_t)128 * 4);
    int2*  csr  = (int2*) alloc((size_t)nnz * 8);        // packed {src, w}
    float* h1   = (float*)alloc((size_t)n * HH * 4);     // born at k_gemm1
    float* g    = (float*)alloc((size_t)n * CC * 4);
    int*   rank = (int*)h1;   // alias: rank (12.8MB) dies at k_fill;
                              // h1 (25.6MB) is written afterwards by k_gemm1
    (void)ws_size;

    const int NB_N  = (n + 255) / 256;
    const int NB_E4 = (nnz / 4 + 255) / 256;   // 3125 (nnz divisible by 4)
    const int NB_SC = (n + 1023) / 1024;       // 98

    k_zero  <<<NB_N, 256, 0, stream>>>(cnt, n);
    k_count <<<NB_E4, 256, 0, stream>>>(ecol, cnt, rank, nnz / 4);
    scan_k1 <<<NB_SC, 256, 0, stream>>>(cnt, offs, bsum, n);
    scan_k2 <<<1, 64, 0, stream>>>(bsum, NB_SC, offs, n);
    scan_k3 <<<NB_N, 256, 0, stream>>>(offs, bsum, n);
    k_fill  <<<NB_E4, 256, 0, stream>>>(erow, ecol, ew, rank, offs, csr, nnz / 4);
    k_degdis<<<NB_N, 256, 0, stream>>>(offs, csr, dis, n);
    k_gemm1 <<<(n + 63) / 64, 256, 0, stream>>>(x, W1, h1, n);
    k_agg1  <<<(n + 3) / 4, 256, 0, stream>>>(h1, offs, csr, dis, b1, W2, g, n);
    k_agg2  <<<(n + 3) / 4, 256, 0, stream>>>(g, offs, csr, dis, b2, out, n);
}

// Round 6
// 623.121 us; speedup vs baseline: 1.4221x; 1.0108x over previous
//
#include <hip/hip_runtime.h>
#include <hip/hip_bf16.h>
#include <cstdint>

// Problem constants (match reference)
#define NN   100000   // nodes
#define DD   128      // in features
#define HH   64       // hidden
#define CC   40       // classes
#define NNZE 3200000  // edges
#define CSTR 32       // counter stride (32 ints = 128B = 1 L2 line per counter)

// ---------------- histogram: padded counters (1 per 128B line) -------------

__global__ void k_zero(int* cnt, int n) {
    int i = blockIdx.x * blockDim.x + threadIdx.x;
    if (i < n) cnt[i * CSTR] = 0;
}

__global__ void k_count(const int* __restrict__ col, int* cnt, int* rank, int nnz4) {
    int i = blockIdx.x * blockDim.x + threadIdx.x;
    if (i < nnz4) {
        int4 c = ((const int4*)col)[i];
        int r0 = atomicAdd(&cnt[c.x * CSTR], 1);
        int r1 = atomicAdd(&cnt[c.y * CSTR], 1);
        int r2 = atomicAdd(&cnt[c.z * CSTR], 1);
        int r3 = atomicAdd(&cnt[c.w * CSTR], 1);
        ((int4*)rank)[i] = make_int4(r0, r1, r2, r3);
    }
}

// ---------------- exclusive scan of cnt -> offs (3 kernels) ----------------
// tile = 1024 elements per block (256 threads x 4); cnt is CSTR-strided

__global__ void scan_k1(const int* __restrict__ cnt, int* offs, int* bsum, int n) {
    __shared__ int s[256];
    int t = threadIdx.x, b = blockIdx.x;
    int base = b * 1024 + t * 4;
    int v0 = (base + 0 < n) ? cnt[(base + 0) * CSTR] : 0;
    int v1 = (base + 1 < n) ? cnt[(base + 1) * CSTR] : 0;
    int v2 = (base + 2 < n) ? cnt[(base + 2) * CSTR] : 0;
    int v3 = (base + 3 < n) ? cnt[(base + 3) * CSTR] : 0;
    int tsum = v0 + v1 + v2 + v3;
    s[t] = tsum;
    __syncthreads();
    for (int off = 1; off < 256; off <<= 1) {
        int x = (t >= off) ? s[t - off] : 0;
        __syncthreads();
        s[t] += x;
        __syncthreads();
    }
    int incl = s[t];
    int p = incl - tsum;  // exclusive base for this thread
    if (base + 0 < n) offs[base + 0] = p; p += v0;
    if (base + 1 < n) offs[base + 1] = p; p += v1;
    if (base + 2 < n) offs[base + 2] = p; p += v2;
    if (base + 3 < n) offs[base + 3] = p;
    if (t == 255) bsum[b] = incl;  // block total
}

__global__ void scan_k2(int* bsum, int nb, int* offs, int n) {
    if (threadIdx.x == 0 && blockIdx.x == 0) {
        int run = 0;
        for (int i = 0; i < nb; i++) { int v = bsum[i]; bsum[i] = run; run += v; }
        offs[n] = run;  // total edge count
    }
}

__global__ void scan_k3(int* offs, const int* __restrict__ bsum, int n) {
    int i = blockIdx.x * blockDim.x + threadIdx.x;
    if (i < n) offs[i] += bsum[i >> 10];
}

// -------- CSR fill (atomic-free, packed int2 {src, w}, 4 edges/thread) -----

__global__ void k_fill(const int* __restrict__ row, const int* __restrict__ col,
                       const float* __restrict__ w, const int* __restrict__ rank,
                       const int* __restrict__ offs,
                       int2* __restrict__ csr, int nnz4) {
    int i = blockIdx.x * blockDim.x + threadIdx.x;
    if (i < nnz4) {
        int4   r  = ((const int4*)row)[i];
        int4   c  = ((const int4*)col)[i];
        int4   rk = ((const int4*)rank)[i];
        float4 wv = ((const float4*)w)[i];
        csr[offs[c.x] + rk.x] = make_int2(r.x, __float_as_int(wv.x));
        csr[offs[c.y] + rk.y] = make_int2(r.y, __float_as_int(wv.y));
        csr[offs[c.z] + rk.z] = make_int2(r.z, __float_as_int(wv.z));
        csr[offs[c.w] + rk.w] = make_int2(r.w, __float_as_int(wv.w));
    }
}

// ---------------- deg -> dis (per-node contiguous sum, no atomics) ---------

__global__ void k_degdis(const int* __restrict__ offs, const int2* __restrict__ csr,
                         float* dis, int n) {
    int i = blockIdx.x * blockDim.x + threadIdx.x;
    if (i < n) {
        float s = 1.0f;               // self-loop weight
        int e0 = offs[i], e1 = offs[i + 1];
        for (int j = e0; j < e1; j++) s += __int_as_float(csr[j].y);
        dis[i] = s > 0.f ? rsqrtf(s) : 0.f;
    }
}

// ---------------- GEMM1: h1 = x @ W1  (100000x128 @ 128x64, fp32 vector) ---

__global__ __launch_bounds__(256) void k_gemm1(const float* __restrict__ x,
                                               const float* __restrict__ W1,
                                               float* __restrict__ h1, int n) {
    __shared__ float ws[128 * 64];   // W1 [k][c]
    __shared__ float xs[16 * 129];   // 16 rows, padded stride 129
    int t = threadIdx.x;
    for (int i = t; i < 128 * 64; i += 256) ws[i] = W1[i];
    int row0 = blockIdx.x * 64;
    int r = t >> 4, cg = t & 15;
    for (int p = 0; p < 4; p++) {
        __syncthreads();  // protect xs (and ws on first pass)
        int rbase = row0 + p * 16;
        for (int i = t; i < 512; i += 256) {
            int li = i * 4;
            int rr = li >> 7, kk = li & 127;
            float4 v = make_float4(0.f, 0.f, 0.f, 0.f);
            if (rbase + rr < n) v = *(const float4*)&x[(rbase + rr) * 128 + kk];
            xs[rr * 129 + kk + 0] = v.x;
            xs[rr * 129 + kk + 1] = v.y;
            xs[rr * 129 + kk + 2] = v.z;
            xs[rr * 129 + kk + 3] = v.w;
        }
        __syncthreads();
        float4 acc = make_float4(0.f, 0.f, 0.f, 0.f);
        for (int k = 0; k < 128; k++) {
            float xa = xs[r * 129 + k];
            float4 w4 = *(const float4*)&ws[k * 64 + cg * 4];
            acc.x += xa * w4.x; acc.y += xa * w4.y;
            acc.z += xa * w4.z; acc.w += xa * w4.w;
        }
        int rowi = rbase + r;
        if (rowi < n) *(float4*)&h1[rowi * 64 + cg * 4] = acc;
    }
}

// ------- agg1 + bias + relu + matvec W2 fused: g = relu(A~ h1 + b1) @ W2 ----
// one wave per destination node; lane = feature (H=64)
// dis[src] folded into staging

__global__ __launch_bounds__(256) void k_agg1(const float* __restrict__ h1,
                                              const int* __restrict__ offs,
                                              const int2* __restrict__ csr,
                                              const float* __restrict__ dis,
                                              const float* __restrict__ b1,
                                              const float* __restrict__ W2,
                                              float* __restrict__ g, int n) {
    __shared__ float w2s[64 * 40];
    __shared__ float sh2[4][64];
    __shared__ int   ssrc[4][64];
    __shared__ float sa[4][64];
    int t = threadIdx.x;
    for (int i = t; i < 64 * 40; i += 256) w2s[i] = W2[i];
    __syncthreads();
    int w = t >> 6, l = t & 63;
    int c = blockIdx.x * 4 + w;
    if (c >= n) return;
    float dc = dis[c];
    float selfh = h1[c * 64 + l];
    float acc = 0.f;
    int start = offs[c], end = offs[c + 1];
    for (int base = start; base < end; base += 64) {
        int m = end - base; if (m > 64) m = 64;
        if (l < m) {
            int2 pk = csr[base + l];
            ssrc[w][l] = pk.x;
            sa[w][l] = __int_as_float(pk.y) * dis[pk.x];
        }
        for (int j = 0; j < m; j++) {
            acc += sa[w][j] * h1[ssrc[w][j] * 64 + l];
        }
    }
    float hv = dc * acc + dc * dc * selfh + b1[l];
    hv = hv > 0.f ? hv : 0.f;
    sh2[w][l] = hv;
    if (l < 40) {
        float gv = 0.f;
        for (int k = 0; k < 64; k++) gv += sh2[w][k] * w2s[k * 40 + l];
        g[c * 40 + l] = gv;
    }
}

// ---------------- agg2 + bias: out = A~ g + b2 ----------------

__global__ __launch_bounds__(256) void k_agg2(const float* __restrict__ g,
                                              const int* __restrict__ offs,
                                              const int2* __restrict__ csr,
                                              const float* __restrict__ dis,
                                              const float* __restrict__ b2,
                                              float* __restrict__ out, int n) {
    __shared__ int   ssrc[4][64];
    __shared__ float sa[4][64];
    int t = threadIdx.x;
    int w = t >> 6, l = t & 63;
    int c = blockIdx.x * 4 + w;
    if (c >= n) return;
    float dc = dis[c];
    float acc = 0.f;
    int start = offs[c], end = offs[c + 1];
    for (int base = start; base < end; base += 64) {
        int m = end - base; if (m > 64) m = 64;
        if (l < m) {
            int2 pk = csr[base + l];
            ssrc[w][l] = pk.x;
            sa[w][l] = __int_as_float(pk.y) * dis[pk.x];
        }
        if (l < 40) {
            for (int j = 0; j < m; j++) {
                acc += sa[w][j] * g[ssrc[w][j] * 40 + l];
            }
        }
    }
    if (l < 40) {
        float selfg = g[c * 40 + l];
        out[c * 40 + l] = dc * acc + dc * dc * selfg + b2[l];
    }
}

// ---------------- launch ----------------

extern "C" void kernel_launch(void* const* d_in, const int* in_sizes, int n_in,
                              void* d_out, int out_size, void* d_ws, size_t ws_size,
                              hipStream_t stream) {
    const float* x  = (const float*)d_in[0];
    const int*   ei = (const int*)d_in[1];       // (2, NNZ): [0]=row(src), [1]=col(dst)
    const float* ew = (const float*)d_in[2];
    const float* W1 = (const float*)d_in[3];
    const float* b1 = (const float*)d_in[4];
    const float* W2 = (const float*)d_in[5];
    const float* b2 = (const float*)d_in[6];
    float* out = (float*)d_out;

    const int n = NN, nnz = NNZE;
    const int* erow = ei;
    const int* ecol = ei + nnz;

    // workspace layout (lifetime-aware aliasing; footprint unchanged ~68MB)
    char* p = (char*)d_ws;
    auto alloc = [&](size_t bytes) {
        void* r = (void*)p;
        p += (bytes + 255) & ~(size_t)255;
        return r;
    };
    float* dis  = (float*)alloc((size_t)n * 4);
    int*   offs = (int*)  alloc((size_t)(n + 1) * 4);
    int*   bsum = (int*)  alloc((size_t)128 * 4);
    int2*  csr  = (int2*) alloc((size_t)nnz * 8);        // packed {src, w}
    float* h1   = (float*)alloc((size_t)n * HH * 4);     // born at k_gemm1
    float* g    = (float*)alloc((size_t)n * CC * 4);     // born at k_agg1
    int*   rank = (int*)h1;  // alias: rank (12.8MB) dies at k_fill; h1 born at k_gemm1
    int*   cnt  = (int*)g;   // alias: padded cnt (100k*128B=12.8MB <= 16MB) dies
                             // after scan_k1; g born at k_agg1
    (void)ws_size;

    const int NB_N  = (n + 255) / 256;
    const int NB_E4 = (nnz / 4 + 255) / 256;   // 3125 (nnz divisible by 4)
    const int NB_SC = (n + 1023) / 1024;       // 98

    k_zero  <<<NB_N, 256, 0, stream>>>(cnt, n);
    k_count <<<NB_E4, 256, 0, stream>>>(ecol, cnt, rank, nnz / 4);
    scan_k1 <<<NB_SC, 256, 0, stream>>>(cnt, offs, bsum, n);
    scan_k2 <<<1, 64, 0, stream>>>(bsum, NB_SC, offs, n);
    scan_k3 <<<NB_N, 256, 0, stream>>>(offs, bsum, n);
    k_fill  <<<NB_E4, 256, 0, stream>>>(erow, ecol, ew, rank, offs, csr, nnz / 4);
    k_degdis<<<NB_N, 256, 0, stream>>>(offs, csr, dis, n);
    k_gemm1 <<<(n + 63) / 64, 256, 0, stream>>>(x, W1, h1, n);
    k_agg1  <<<(n + 3) / 4, 256, 0, stream>>>(h1, offs, csr, dis, b1, W2, g, n);
    k_agg2  <<<(n + 3) / 4, 256, 0, stream>>>(g, offs, csr, dis, b2, out, n);
}

// Round 7
// 578.000 us; speedup vs baseline: 1.5331x; 1.0781x over previous
//
#include <hip/hip_runtime.h>
#include <hip/hip_bf16.h>
#include <hip/hip_fp16.h>
#include <cstdint>

// Problem constants (match reference)
#define NN   100000   // nodes
#define DD   128      // in features
#define HH   64       // hidden
#define CC   40       // classes
#define NNZE 3200000  // edges
#define CSTR 32       // counter stride (32 ints = 128B = 1 L2 line per counter)

// ---------------- histogram: padded counters (1 per 128B line) -------------

__global__ void k_zero(int* cnt, int n) {
    int i = blockIdx.x * blockDim.x + threadIdx.x;
    if (i < n) cnt[i * CSTR] = 0;
}

__global__ void k_count(const int* __restrict__ col, int* cnt, int* rank, int nnz4) {
    int i = blockIdx.x * blockDim.x + threadIdx.x;
    if (i < nnz4) {
        int4 c = ((const int4*)col)[i];
        int r0 = atomicAdd(&cnt[c.x * CSTR], 1);
        int r1 = atomicAdd(&cnt[c.y * CSTR], 1);
        int r2 = atomicAdd(&cnt[c.z * CSTR], 1);
        int r3 = atomicAdd(&cnt[c.w * CSTR], 1);
        ((int4*)rank)[i] = make_int4(r0, r1, r2, r3);
    }
}

// ---------------- exclusive scan of cnt -> offs (3 kernels) ----------------
// tile = 1024 elements per block (256 threads x 4); cnt is CSTR-strided

__global__ void scan_k1(const int* __restrict__ cnt, int* offs, int* bsum, int n) {
    __shared__ int s[256];
    int t = threadIdx.x, b = blockIdx.x;
    int base = b * 1024 + t * 4;
    int v0 = (base + 0 < n) ? cnt[(base + 0) * CSTR] : 0;
    int v1 = (base + 1 < n) ? cnt[(base + 1) * CSTR] : 0;
    int v2 = (base + 2 < n) ? cnt[(base + 2) * CSTR] : 0;
    int v3 = (base + 3 < n) ? cnt[(base + 3) * CSTR] : 0;
    int tsum = v0 + v1 + v2 + v3;
    s[t] = tsum;
    __syncthreads();
    for (int off = 1; off < 256; off <<= 1) {
        int x = (t >= off) ? s[t - off] : 0;
        __syncthreads();
        s[t] += x;
        __syncthreads();
    }
    int incl = s[t];
    int p = incl - tsum;  // exclusive base for this thread
    if (base + 0 < n) offs[base + 0] = p; p += v0;
    if (base + 1 < n) offs[base + 1] = p; p += v1;
    if (base + 2 < n) offs[base + 2] = p; p += v2;
    if (base + 3 < n) offs[base + 3] = p;
    if (t == 255) bsum[b] = incl;  // block total
}

__global__ void scan_k2(int* bsum, int nb, int* offs, int n) {
    if (threadIdx.x == 0 && blockIdx.x == 0) {
        int run = 0;
        for (int i = 0; i < nb; i++) { int v = bsum[i]; bsum[i] = run; run += v; }
        offs[n] = run;  // total edge count
    }
}

__global__ void scan_k3(int* offs, const int* __restrict__ bsum, int n) {
    int i = blockIdx.x * blockDim.x + threadIdx.x;
    if (i < n) offs[i] += bsum[i >> 10];
}

// -------- CSR fill (atomic-free, packed int2 {src, w}, 4 edges/thread) -----

__global__ void k_fill(const int* __restrict__ row, const int* __restrict__ col,
                       const float* __restrict__ w, const int* __restrict__ rank,
                       const int* __restrict__ offs,
                       int2* __restrict__ csr, int nnz4) {
    int i = blockIdx.x * blockDim.x + threadIdx.x;
    if (i < nnz4) {
        int4   r  = ((const int4*)row)[i];
        int4   c  = ((const int4*)col)[i];
        int4   rk = ((const int4*)rank)[i];
        float4 wv = ((const float4*)w)[i];
        csr[offs[c.x] + rk.x] = make_int2(r.x, __float_as_int(wv.x));
        csr[offs[c.y] + rk.y] = make_int2(r.y, __float_as_int(wv.y));
        csr[offs[c.z] + rk.z] = make_int2(r.z, __float_as_int(wv.z));
        csr[offs[c.w] + rk.w] = make_int2(r.w, __float_as_int(wv.w));
    }
}

// ---------------- deg -> dis (per-node contiguous sum, no atomics) ---------

__global__ void k_degdis(const int* __restrict__ offs, const int2* __restrict__ csr,
                         float* dis, int n) {
    int i = blockIdx.x * blockDim.x + threadIdx.x;
    if (i < n) {
        float s = 1.0f;               // self-loop weight
        int e0 = offs[i], e1 = offs[i + 1];
        for (int j = e0; j < e1; j++) s += __int_as_float(csr[j].y);
        dis[i] = s > 0.f ? rsqrtf(s) : 0.f;
    }
}

// ------- GEMM1: h1 = x @ W1 (100000x128 @ 128x64), fp32 math, fp16 store ---

__global__ __launch_bounds__(256) void k_gemm1(const float* __restrict__ x,
                                               const float* __restrict__ W1,
                                               __half* __restrict__ h1h, int n) {
    __shared__ float ws[128 * 64];   // W1 [k][c]
    __shared__ float xs[16 * 129];   // 16 rows, padded stride 129
    int t = threadIdx.x;
    for (int i = t; i < 128 * 64; i += 256) ws[i] = W1[i];
    int row0 = blockIdx.x * 64;
    int r = t >> 4, cg = t & 15;
    for (int p = 0; p < 4; p++) {
        __syncthreads();  // protect xs (and ws on first pass)
        int rbase = row0 + p * 16;
        for (int i = t; i < 512; i += 256) {
            int li = i * 4;
            int rr = li >> 7, kk = li & 127;
            float4 v = make_float4(0.f, 0.f, 0.f, 0.f);
            if (rbase + rr < n) v = *(const float4*)&x[(rbase + rr) * 128 + kk];
            xs[rr * 129 + kk + 0] = v.x;
            xs[rr * 129 + kk + 1] = v.y;
            xs[rr * 129 + kk + 2] = v.z;
            xs[rr * 129 + kk + 3] = v.w;
        }
        __syncthreads();
        float4 acc = make_float4(0.f, 0.f, 0.f, 0.f);
        for (int k = 0; k < 128; k++) {
            float xa = xs[r * 129 + k];
            float4 w4 = *(const float4*)&ws[k * 64 + cg * 4];
            acc.x += xa * w4.x; acc.y += xa * w4.y;
            acc.z += xa * w4.z; acc.w += xa * w4.w;
        }
        int rowi = rbase + r;
        if (rowi < n) {
            __half2 lo = __floats2half2_rn(acc.x, acc.y);
            __half2 hi = __floats2half2_rn(acc.z, acc.w);
            *(__half2*)&h1h[rowi * 64 + cg * 4 + 0] = lo;
            *(__half2*)&h1h[rowi * 64 + cg * 4 + 2] = hi;
        }
    }
}

// ------- agg1 + bias + relu + matvec W2 fused: g = relu(A~ h1 + b1) @ W2 ----
// one wave per destination node; lane = feature (H=64); h1 gathered as fp16

__global__ __launch_bounds__(256) void k_agg1(const __half* __restrict__ h1h,
                                              const int* __restrict__ offs,
                                              const int2* __restrict__ csr,
                                              const float* __restrict__ dis,
                                              const float* __restrict__ b1,
                                              const float* __restrict__ W2,
                                              __half* __restrict__ gh, int n) {
    __shared__ float w2s[64 * 40];
    __shared__ float sh2[4][64];
    __shared__ int   ssrc[4][64];
    __shared__ float sa[4][64];
    int t = threadIdx.x;
    for (int i = t; i < 64 * 40; i += 256) w2s[i] = W2[i];
    __syncthreads();
    int w = t >> 6, l = t & 63;
    int c = blockIdx.x * 4 + w;
    if (c >= n) return;
    float dc = dis[c];
    float selfh = __half2float(h1h[c * 64 + l]);
    float acc = 0.f;
    int start = offs[c], end = offs[c + 1];
    for (int base = start; base < end; base += 64) {
        int m = end - base; if (m > 64) m = 64;
        if (l < m) {
            int2 pk = csr[base + l];
            ssrc[w][l] = pk.x;
            sa[w][l] = __int_as_float(pk.y) * dis[pk.x];
        }
        for (int j = 0; j < m; j++) {
            acc += sa[w][j] * __half2float(h1h[ssrc[w][j] * 64 + l]);
        }
    }
    float hv = dc * acc + dc * dc * selfh + b1[l];
    hv = hv > 0.f ? hv : 0.f;
    sh2[w][l] = hv;
    if (l < 40) {
        float gv = 0.f;
        for (int k = 0; k < 64; k++) gv += sh2[w][k] * w2s[k * 40 + l];
        gh[c * 40 + l] = __float2half_rn(gv);
    }
}

// ---------------- agg2 + bias: out = A~ g + b2 (g gathered as fp16) --------

__global__ __launch_bounds__(256) void k_agg2(const __half* __restrict__ gh,
                                              const int* __restrict__ offs,
                                              const int2* __restrict__ csr,
                                              const float* __restrict__ dis,
                                              const float* __restrict__ b2,
                                              float* __restrict__ out, int n) {
    __shared__ int   ssrc[4][64];
    __shared__ float sa[4][64];
    int t = threadIdx.x;
    int w = t >> 6, l = t & 63;
    int c = blockIdx.x * 4 + w;
    if (c >= n) return;
    float dc = dis[c];
    float acc = 0.f;
    int start = offs[c], end = offs[c + 1];
    for (int base = start; base < end; base += 64) {
        int m = end - base; if (m > 64) m = 64;
        if (l < m) {
            int2 pk = csr[base + l];
            ssrc[w][l] = pk.x;
            sa[w][l] = __int_as_float(pk.y) * dis[pk.x];
        }
        if (l < 40) {
            for (int j = 0; j < m; j++) {
                acc += sa[w][j] * __half2float(gh[ssrc[w][j] * 40 + l]);
            }
        }
    }
    if (l < 40) {
        float selfg = __half2float(gh[c * 40 + l]);
        out[c * 40 + l] = dc * acc + dc * dc * selfg + b2[l];
    }
}

// ---------------- launch ----------------

extern "C" void kernel_launch(void* const* d_in, const int* in_sizes, int n_in,
                              void* d_out, int out_size, void* d_ws, size_t ws_size,
                              hipStream_t stream) {
    const float* x  = (const float*)d_in[0];
    const int*   ei = (const int*)d_in[1];       // (2, NNZ): [0]=row(src), [1]=col(dst)
    const float* ew = (const float*)d_in[2];
    const float* W1 = (const float*)d_in[3];
    const float* b1 = (const float*)d_in[4];
    const float* W2 = (const float*)d_in[5];
    const float* b2 = (const float*)d_in[6];
    float* out = (float*)d_out;

    const int n = NN, nnz = NNZE;
    const int* erow = ei;
    const int* ecol = ei + nnz;

    // workspace layout (lifetime-aware aliasing)
    char* p = (char*)d_ws;
    auto alloc = [&](size_t bytes) {
        void* r = (void*)p;
        p += (bytes + 255) & ~(size_t)255;
        return r;
    };
    float* dis   = (float*)alloc((size_t)n * 4);
    int*   offs  = (int*)  alloc((size_t)(n + 1) * 4);
    int*   bsum  = (int*)  alloc((size_t)128 * 4);
    int2*  csr   = (int2*) alloc((size_t)nnz * 8);        // packed {src, w}
    // slotA: rank (nnz*4 = 12.8MB, dies at k_fill) then h1h (n*64*2 = 12.8MB)
    void*  slotA = alloc((size_t)nnz * 4);
    // slotB: padded cnt (n*CSTR*4 = 12.8MB, dies after scan_k1) then gh (n*40*2 = 8MB)
    void*  slotB = alloc((size_t)n * CSTR * 4);
    int*    rank = (int*)slotA;
    __half* h1h  = (__half*)slotA;
    int*    cnt  = (int*)slotB;
    __half* gh   = (__half*)slotB;
    (void)ws_size;

    const int NB_N  = (n + 255) / 256;
    const int NB_E4 = (nnz / 4 + 255) / 256;   // 3125 (nnz divisible by 4)
    const int NB_SC = (n + 1023) / 1024;       // 98

    k_zero  <<<NB_N, 256, 0, stream>>>(cnt, n);
    k_count <<<NB_E4, 256, 0, stream>>>(ecol, cnt, rank, nnz / 4);
    scan_k1 <<<NB_SC, 256, 0, stream>>>(cnt, offs, bsum, n);
    scan_k2 <<<1, 64, 0, stream>>>(bsum, NB_SC, offs, n);
    scan_k3 <<<NB_N, 256, 0, stream>>>(offs, bsum, n);
    k_fill  <<<NB_E4, 256, 0, stream>>>(erow, ecol, ew, rank, offs, csr, nnz / 4);
    k_degdis<<<NB_N, 256, 0, stream>>>(offs, csr, dis, n);
    k_gemm1 <<<(n + 63) / 64, 256, 0, stream>>>(x, W1, h1h, n);
    k_agg1  <<<(n + 3) / 4, 256, 0, stream>>>(h1h, offs, csr, dis, b1, W2, gh, n);
    k_agg2  <<<(n + 3) / 4, 256, 0, stream>>>(gh, offs, csr, dis, b2, out, n);
}